// Round 1
// baseline (15.526 us; speedup 1.0000x reference)
//
#include <hip/hip_runtime.h>
#include <hip/hip_bf16.h>

// ZeroOneLoss: out = mean_i( input[i, targets[i]] > 0 )
// B = 16384, V = 32000 (derived from in_sizes at launch time).
//
// Only B scattered floats + B targets are needed -> latency/launch-overhead
// bound. Integer atomic count => deterministic across graph replays.

__global__ void zol_gather_count(const float* __restrict__ input,
                                 const int* __restrict__ targets,
                                 int* __restrict__ count,
                                 int B, long long V) {
    int i = blockIdx.x * blockDim.x + threadIdx.x;
    bool pred = false;
    if (i < B) {
        int t = targets[i];
        float v = input[(long long)i * V + (long long)t];
        pred = (v > 0.0f);
    }
    // 64-lane wave ballot + popcount; one atomic per wave.
    unsigned long long mask = __ballot(pred);
    if ((threadIdx.x & 63) == 0) {
        atomicAdd(count, (int)__popcll(mask));
    }
}

__global__ void zol_finalize(const int* __restrict__ count,
                             float* __restrict__ out, float inv_B) {
    out[0] = (float)(*count) * inv_B;
}

extern "C" void kernel_launch(void* const* d_in, const int* in_sizes, int n_in,
                              void* d_out, int out_size, void* d_ws, size_t ws_size,
                              hipStream_t stream) {
    const float* input = (const float*)d_in[0];
    const int* targets = (const int*)d_in[1];
    float* out = (float*)d_out;

    const int B = in_sizes[1];                 // 16384
    const long long V = (long long)in_sizes[0] / (long long)B;  // 32000

    int* count = (int*)d_ws;

    // Zero the counter every call (harness poisons ws once, never re-poisons).
    hipMemsetAsync(count, 0, sizeof(int), stream);

    const int block = 64;
    const int grid = (B + block - 1) / block;  // 256 blocks, 1 wave each
    zol_gather_count<<<grid, block, 0, stream>>>(input, targets, count, B, V);

    zol_finalize<<<1, 1, 0, stream>>>(count, out, 1.0f / (float)B);
}